// Round 2
// baseline (484.772 us; speedup 1.0000x reference)
//
#include <hip/hip_runtime.h>
#include <hip/hip_bf16.h>

// GCN on MI355X. Pipeline (8 launches + memset):
//   initcur + bin_edges (fixed-cap buckets) + build_rows : CSR by dst (ushort colidx)
//   prep_wt        : W1,W2 -> bf16 transposed [n][k] (MFMA B-operand layout)
//   gemm_mfma<f32> : h1' = dinv ⊙ (x@W1)             -> bufA (bf16, GRANULE-major)
//   agg_mid_c      : a1 = relu(di*(self+Σ h1') + b1)  -> bufB (bf16, GRANULE-major)
//   gemm_mfma<bf16>: h2' = dinv ⊙ (a1@W2)            -> bufA (bf16, GRANULE-major)
//   memset out = 0
//   agg_fin_c      : a2 = relu(di*(self+Σ h2') + b2); atomicAdd partial a2@Wc (+bc on chunk 0)
//
// Granule-major h layout: H[g][node][8 feats], g in 0..15, one uint4 (16B) per entry.
// Aggregation is FEATURE-CHUNKED: block handles chunk f = blockIdx.x & 7
// (granules 2f, 2f+1) for 128 nodes; with round-robin block->XCD dispatch all
// blocks of chunk f land on XCD f, whose gather working set is 2 x 800KB =
// 1.6MB -> L2-resident (vs 12.8MB full rows before; agg was L2-capacity bound,
// FETCH_SIZE 160MB @ 2.76 TB/s). Every 128B line fetched is 100% same-chunk
// useful. colidx is ushort (n <= 65536) to halve the 8x-replicated stream.
// Per node: 2 lanes x uint4; unmasked 8-edge main loop (8 loads in flight),
// one masked-8 tail (dummy = self row, compensated analytically).
// GEMMs: mfma_f32_16x16x32_bf16, wave = 16 rows x 128 cols. Requires n <= 65536.

typedef unsigned int uint;
typedef unsigned short ushort;
typedef __attribute__((ext_vector_type(8))) short bf16x8;
typedef __attribute__((ext_vector_type(4))) float f32x4;

#define NPB 256
#define MAXBKT 256
#define CAP 12288   // edges per bucket region; mean 8192, sd ~90

static __device__ __forceinline__ ushort f2bf(float f) {
    unsigned u = __float_as_uint(f);
    u += 0x7fffu + ((u >> 16) & 1u);   // round-to-nearest-even
    return (ushort)(u >> 16);
}
static __device__ __forceinline__ uint pack2(float a, float b) {
    return (uint)f2bf(a) | ((uint)f2bf(b) << 16);
}
static __device__ __forceinline__ float lo2f(uint u) { return __uint_as_float(u << 16); }
static __device__ __forceinline__ float hi2f(uint u) { return __uint_as_float(u & 0xffff0000u); }

#define UNPACK8(dst, u)                                        \
    dst[0] = lo2f(u.x); dst[1] = hi2f(u.x);                    \
    dst[2] = lo2f(u.y); dst[3] = hi2f(u.y);                    \
    dst[4] = lo2f(u.z); dst[5] = hi2f(u.z);                    \
    dst[6] = lo2f(u.w); dst[7] = hi2f(u.w);

// ---------------- CSR build (fixed-capacity buckets) ----------------

__global__ __launch_bounds__(256) void initcur(int* __restrict__ bcursor, int nbuckets) {
    int t = threadIdx.x;
    if (t < nbuckets) bcursor[t] = t * CAP;
}

__global__ __launch_bounds__(256) void bin_edges(const int* __restrict__ src,
                                                 const int* __restrict__ dst,
                                                 int* __restrict__ bcursor,
                                                 uint* __restrict__ pay,
                                                 int E, int nbuckets) {
    __shared__ int h[MAXBKT];
    __shared__ int base[MAXBKT];
    int tid = threadIdx.x;
    h[tid] = 0;
    __syncthreads();
    int chunk = (E + gridDim.x - 1) / gridDim.x;
    int i0 = blockIdx.x * chunk;
    int i1 = min(E, i0 + chunk);
    for (int i = i0 + tid; i < i1; i += 256) atomicAdd(&h[dst[i] >> 8], 1);
    __syncthreads();
    if (tid < nbuckets) base[tid] = h[tid] ? atomicAdd(&bcursor[tid], h[tid]) : 0;
    __syncthreads();
    h[tid] = 0;
    __syncthreads();
    for (int i = i0 + tid; i < i1; i += 256) {
        int d = dst[i];
        int b = d >> 8;
        int pos = base[b] + atomicAdd(&h[b], 1);
        pay[pos] = (uint)src[i] | ((uint)(d & 255) << 24);
    }
}

__global__ __launch_bounds__(256) void build_rows(const uint* __restrict__ pay,
                                                  const int* __restrict__ bcursor,
                                                  int* __restrict__ rowstart,
                                                  int* __restrict__ rowend,
                                                  float* __restrict__ dinv,
                                                  ushort* __restrict__ colidx, int n) {
    __shared__ int hist[NPB];
    __shared__ int sc[NPB];
    __shared__ int cur[NPB];
    int tid = threadIdx.x;
    int b = blockIdx.x;
    int node0 = b * NPB;
    int s = b * CAP, e = bcursor[b];

    hist[tid] = 0;
    __syncthreads();
    for (int i = s + tid; i < e; i += 256) atomicAdd(&hist[pay[i] >> 24], 1);
    __syncthreads();

    int v = hist[tid];
    sc[tid] = v;
    __syncthreads();
    for (int d = 1; d < 256; d <<= 1) {
        int x = (tid >= d) ? sc[tid - d] : 0;
        __syncthreads();
        sc[tid] += x;
        __syncthreads();
    }
    int excl = sc[tid] - v;
    cur[tid] = s + excl;
    int node = node0 + tid;
    if (node < n) {
        rowstart[node] = s + excl;
        rowend[node] = s + excl + v;
        dinv[node] = rsqrtf((float)(v + 1));  // +1 self-loop
    }
    __syncthreads();

    for (int i = s + tid; i < e; i += 256) {
        uint p = pay[i];
        int pos = atomicAdd(&cur[p >> 24], 1);
        colidx[pos] = (ushort)p;   // src < 65536
    }
}

// ---------------- W prep: bf16 transpose [n][k] for MFMA B-operand ----------
__global__ __launch_bounds__(256) void prep_wt(const float* __restrict__ W1,
                                               const float* __restrict__ W2,
                                               ushort* __restrict__ Wt1,
                                               ushort* __restrict__ Wt2) {
    int idx = blockIdx.x * 256 + threadIdx.x;  // 0..16383
    int k = idx >> 7, nn = idx & 127;
    Wt1[nn * 128 + k] = f2bf(W1[idx]);
    Wt2[nn * 128 + k] = f2bf(W2[idx]);
}

// ------- MFMA GEMM: Y = dinv ⊙ (X @ W), bf16 packed, GRANULE-major output -------
// Block 256 = 4 waves; wave computes 16 rows x 128 cols.
// mfma_f32_16x16x32_bf16 layouts (verified learn_hip m89/m120):
//   A[m][k]: m=lane&15, k=quad*8+j    B[k][n]: n=lane&15, k=quad*8+j
//   C/D:     col=lane&15, row=quad*4+reg
// A (when bf16) is read from granule-major [g][node][8], g = ks*4+quad.
// Output written granule-major: uint4 at Yg[g*n + row].
template <bool A_BF16>
__global__ __launch_bounds__(256) void gemm_mfma(const void* __restrict__ Xv,
                                                 const ushort* __restrict__ Wt,
                                                 const float* __restrict__ dinv,
                                                 uint* __restrict__ Yb, int n) {
    __shared__ __align__(16) ushort sOut[4][16][136];  // pad: 272B row stride
    const int wave = threadIdx.x >> 6;
    const int lane = threadIdx.x & 63;
    const int quad = lane >> 4, l16 = lane & 15;
    const int m0 = blockIdx.x * 64 + wave * 16;

    f32x4 acc[8];
#pragma unroll
    for (int t = 0; t < 8; ++t) acc[t] = (f32x4){0.f, 0.f, 0.f, 0.f};

    int arow = m0 + l16;
    arow = arow < n ? arow : n - 1;

#pragma unroll
    for (int ks = 0; ks < 4; ++ks) {
        bf16x8 a;
        if (A_BF16) {
            const ushort* X = (const ushort*)Xv;
            // granule-major: g = ks*4 + quad, entry = 8 ushorts
            a = *(const bf16x8*)&X[((size_t)(ks * 4 + quad) * n + arow) * 8];
        } else {
            const float* X = (const float*)Xv;
            const float* px = &X[(size_t)arow * 128 + ks * 32 + quad * 8];
            float4 x0 = *(const float4*)px;
            float4 x1 = *(const float4*)(px + 4);
            ushort av[8] = {f2bf(x0.x), f2bf(x0.y), f2bf(x0.z), f2bf(x0.w),
                            f2bf(x1.x), f2bf(x1.y), f2bf(x1.z), f2bf(x1.w)};
            a = *(const bf16x8*)av;
        }
#pragma unroll
        for (int nt = 0; nt < 8; ++nt) {
            bf16x8 b = *(const bf16x8*)&Wt[(size_t)(nt * 16 + l16) * 128 + ks * 32 + quad * 8];
            acc[nt] = __builtin_amdgcn_mfma_f32_16x16x32_bf16(a, b, acc[nt], 0, 0, 0);
        }
    }

    // epilogue: scale rows by dinv, pack bf16 into LDS, granule-major store
    float dv[4];
#pragma unroll
    for (int r = 0; r < 4; ++r) {
        int rr = m0 + quad * 4 + r;
        dv[r] = dinv[rr < n ? rr : n - 1];
    }
#pragma unroll
    for (int nt = 0; nt < 8; ++nt)
#pragma unroll
        for (int r = 0; r < 4; ++r)
            sOut[wave][quad * 4 + r][nt * 16 + l16] = f2bf(acc[nt][r] * dv[r]);
    __syncthreads();

#pragma unroll
    for (int i = 0; i < 4; ++i) {
        int linear = i * 64 + lane;
        int g = linear >> 4, row = linear & 15;   // 16 consecutive rows per 16-lane group
        int rr = m0 + row;
        if (rr < n) {
            uint4 v = *(const uint4*)&sOut[wave][row][g * 8];
            *(uint4*)&Yb[((size_t)g * n + rr) * 4] = v;
        }
    }
}

// ------------- aggregate core: one node per LANE PAIR, one 16-feature chunk -------------
// Hg: uint4 view of granule-major h buffer; gbase = (size_t)g * n.
// Unmasked 8-edge main loop (8 rows in flight), one masked-8 tail iteration
// with dummy = self row (L2/L1-hot) compensated by acc -= pad * t.
static __device__ __forceinline__ void gather_g(const uint4* __restrict__ Hg,
                                                int s, int e, int nn, size_t gbase,
                                                const ushort* __restrict__ colidx,
                                                float acc[8]) {
    uint4 su = Hg[gbase + nn];
    float t[8];
    UNPACK8(t, su);
#pragma unroll
    for (int j = 0; j < 8; ++j) acc[j] = t[j];   // self term (pre-scaled h')

    int p = s;
    for (; p + 8 <= e; p += 8) {
        int c[8];
#pragma unroll
        for (int i = 0; i < 8; ++i) c[i] = colidx[p + i];
        uint4 u[8];
#pragma unroll
        for (int i = 0; i < 8; ++i) u[i] = Hg[gbase + c[i]];
#pragma unroll
        for (int i = 0; i < 8; ++i) {
            float a[8];
            UNPACK8(a, u[i]);
#pragma unroll
            for (int j = 0; j < 8; ++j) acc[j] += a[j];
        }
    }
    if (p < e) {
        int c[8];
#pragma unroll
        for (int i = 0; i < 8; ++i) c[i] = (p + i < e) ? (int)colidx[p + i] : nn;
        uint4 u[8];
#pragma unroll
        for (int i = 0; i < 8; ++i) u[i] = Hg[gbase + c[i]];
#pragma unroll
        for (int i = 0; i < 8; ++i) {
            float a[8];
            UNPACK8(a, u[i]);
#pragma unroll
            for (int j = 0; j < 8; ++j) acc[j] += a[j];
        }
        float pad = (float)(p + 8 - e);   // dummies added self row 'pad' times
#pragma unroll
        for (int j = 0; j < 8; ++j) acc[j] -= pad * t[j];
    }
}

// middle layer: a1 = relu(di*sum + b1), bf16 granule-major. chunk f = blockIdx&7,
// 128 nodes/block, 2 lanes/node (sub = tid&1 -> granule g = 2f+sub).
__global__ __launch_bounds__(256) void agg_mid_c(const uint4* __restrict__ Hg,
                                                 const int* __restrict__ rowstart,
                                                 const int* __restrict__ rowend,
                                                 const ushort* __restrict__ colidx,
                                                 const float* __restrict__ dinv,
                                                 const float* __restrict__ bias,
                                                 uint4* __restrict__ Og, int n) {
    int tid = threadIdx.x;
    int sub = tid & 1;
    int f = blockIdx.x & 7;                       // chunk -> XCD (round-robin dispatch)
    int node = (blockIdx.x >> 3) * 128 + (tid >> 1);
    int nn = node < n ? node : n - 1;
    int s = rowstart[nn], e = rowend[nn];
    float di = dinv[nn];
    int g = f * 2 + sub;
    size_t gbase = (size_t)g * n;

    float acc[8];
    gather_g(Hg, s, e, nn, gbase, colidx, acc);

    if (node < n) {
        const float4* B4 = (const float4*)bias;
        float4 b0 = B4[g * 2];
        float4 b1 = B4[g * 2 + 1];
        float o0 = fmaxf(fmaf(acc[0], di, b0.x), 0.f);
        float o1 = fmaxf(fmaf(acc[1], di, b0.y), 0.f);
        float o2 = fmaxf(fmaf(acc[2], di, b0.z), 0.f);
        float o3 = fmaxf(fmaf(acc[3], di, b0.w), 0.f);
        float o4 = fmaxf(fmaf(acc[4], di, b1.x), 0.f);
        float o5 = fmaxf(fmaf(acc[5], di, b1.y), 0.f);
        float o6 = fmaxf(fmaf(acc[6], di, b1.z), 0.f);
        float o7 = fmaxf(fmaf(acc[7], di, b1.w), 0.f);
        uint4 ov;
        ov.x = pack2(o0, o1); ov.y = pack2(o2, o3);
        ov.z = pack2(o4, o5); ov.w = pack2(o6, o7);
        Og[gbase + node] = ov;
    }
}

// final layer + fused classifier partial: a2 stays f32 in registers; each chunk
// computes a2[16] (2 lanes x 8) and atomicAdds its 16x16 Wc partial into out.
// chunk 0 also adds bc. out must be zeroed before this kernel.
__global__ __launch_bounds__(256) void agg_fin_c(const uint4* __restrict__ Hg,
                                                 const int* __restrict__ rowstart,
                                                 const int* __restrict__ rowend,
                                                 const ushort* __restrict__ colidx,
                                                 const float* __restrict__ dinv,
                                                 const float* __restrict__ bias,
                                                 const float* __restrict__ Wc,
                                                 const float* __restrict__ bc,
                                                 float* __restrict__ out, int n) {
    int tid = threadIdx.x;
    int sub = tid & 1;
    int f = blockIdx.x & 7;
    int node = (blockIdx.x >> 3) * 128 + (tid >> 1);
    int nn = node < n ? node : n - 1;
    int s = rowstart[nn], e = rowend[nn];
    float di = dinv[nn];
    int g = f * 2 + sub;
    size_t gbase = (size_t)g * n;

    float acc[8];
    gather_g(Hg, s, e, nn, gbase, colidx, acc);

    float a[8];
    {
        const float4* B4 = (const float4*)bias;
        float4 b0 = B4[g * 2];
        float4 b1 = B4[g * 2 + 1];
        a[0] = fmaxf(fmaf(acc[0], di, b0.x), 0.f);
        a[1] = fmaxf(fmaf(acc[1], di, b0.y), 0.f);
        a[2] = fmaxf(fmaf(acc[2], di, b0.z), 0.f);
        a[3] = fmaxf(fmaf(acc[3], di, b0.w), 0.f);
        a[4] = fmaxf(fmaf(acc[4], di, b1.x), 0.f);
        a[5] = fmaxf(fmaf(acc[5], di, b1.y), 0.f);
        a[6] = fmaxf(fmaf(acc[6], di, b1.z), 0.f);
        a[7] = fmaxf(fmaf(acc[7], di, b1.w), 0.f);
    }

    // partial dot: this lane covers Wc rows g*8 .. g*8+7 (L1-broadcast loads)
    float p[16];
#pragma unroll
    for (int c = 0; c < 16; ++c) p[c] = 0.f;
#pragma unroll
    for (int j = 0; j < 8; ++j) {
        const float4* wr = (const float4*)&Wc[(size_t)(g * 8 + j) * 16];
        float4 w0 = wr[0], w1 = wr[1], w2 = wr[2], w3 = wr[3];
        float aj = a[j];
        p[0]  = fmaf(aj, w0.x, p[0]);  p[1]  = fmaf(aj, w0.y, p[1]);
        p[2]  = fmaf(aj, w0.z, p[2]);  p[3]  = fmaf(aj, w0.w, p[3]);
        p[4]  = fmaf(aj, w1.x, p[4]);  p[5]  = fmaf(aj, w1.y, p[5]);
        p[6]  = fmaf(aj, w1.z, p[6]);  p[7]  = fmaf(aj, w1.w, p[7]);
        p[8]  = fmaf(aj, w2.x, p[8]);  p[9]  = fmaf(aj, w2.y, p[9]);
        p[10] = fmaf(aj, w2.z, p[10]); p[11] = fmaf(aj, w2.w, p[11]);
        p[12] = fmaf(aj, w3.x, p[12]); p[13] = fmaf(aj, w3.y, p[13]);
        p[14] = fmaf(aj, w3.z, p[14]); p[15] = fmaf(aj, w3.w, p[15]);
    }
    // combine lane pair (feats 0..7 + feats 8..15)
#pragma unroll
    for (int c = 0; c < 16; ++c) p[c] += __shfl_xor(p[c], 1);

    if (node < n) {
        int cb = sub * 8;  // lane 0 -> cols 0..7, lane 1 -> cols 8..15
#pragma unroll
        for (int k = 0; k < 8; ++k) {
            float v = p[cb + k];
            if (f == 0) v += bc[cb + k];
            atomicAdd(&out[(size_t)node * 16 + cb + k], v);
        }
    }
}

// ---------------- launch ----------------

extern "C" void kernel_launch(void* const* d_in, const int* in_sizes, int n_in,
                              void* d_out, int out_size, void* d_ws, size_t ws_size,
                              hipStream_t stream) {
    const float* x  = (const float*)d_in[0];
    const int*   ei = (const int*)d_in[1];
    const float* W1 = (const float*)d_in[2];
    const float* b1 = (const float*)d_in[3];
    const float* W2 = (const float*)d_in[4];
    const float* b2 = (const float*)d_in[5];
    const float* Wc = (const float*)d_in[6];
    const float* bc = (const float*)d_in[7];
    float* out = (float*)d_out;

    const int n = in_sizes[0] / 128;  // 50000
    const int E = in_sizes[1] / 2;    // 1,600,000
    const int* src = ei;
    const int* dst = ei + E;
    const int nbuckets = (n + NPB - 1) / NPB;  // 196

    char* p = (char*)d_ws;
    auto alloc = [&](size_t bytes) {
        char* q = p;
        p += (bytes + 255) & ~(size_t)255;
        return q;
    };
    int*    bcursor  = (int*)alloc(MAXBKT * 4);
    int*    rowstart = (int*)alloc((size_t)n * 4);
    int*    rowend   = (int*)alloc((size_t)n * 4);
    float*  dinv     = (float*)alloc((size_t)n * 4);
    ushort* Wt1      = (ushort*)alloc(128 * 128 * 2);
    ushort* Wt2      = (ushort*)alloc(128 * 128 * 2);
    uint*   pay      = (uint*)alloc((size_t)nbuckets * CAP * 4);
    ushort* colidx   = (ushort*)alloc((size_t)nbuckets * CAP * 2);
    uint*   bufA     = (uint*)alloc((size_t)n * 64 * 4);  // bf16 h' (granule-major)
    uint*   bufB     = (uint*)alloc((size_t)n * 64 * 4);  // bf16 a1 (granule-major)
    if ((size_t)(p - (char*)d_ws) > ws_size) return;

    hipMemsetAsync(out, 0, (size_t)n * 16 * sizeof(float), stream);

    initcur<<<1, 256, 0, stream>>>(bcursor, nbuckets);
    bin_edges<<<256, 256, 0, stream>>>(src, dst, bcursor, pay, E, nbuckets);
    build_rows<<<nbuckets, 256, 0, stream>>>(pay, bcursor, rowstart, rowend, dinv, colidx, n);
    prep_wt<<<64, 256, 0, stream>>>(W1, W2, Wt1, Wt2);

    const int gemmb = (n + 63) / 64;
    const int aggb = 8 * ((n + 127) / 128);   // 8 feature chunks x node blocks
    gemm_mfma<false><<<gemmb, 256, 0, stream>>>(x, Wt1, dinv, bufA, n);
    agg_mid_c<<<aggb, 256, 0, stream>>>((const uint4*)bufA, rowstart, rowend, colidx,
                                        dinv, b1, (uint4*)bufB, n);
    gemm_mfma<true><<<gemmb, 256, 0, stream>>>(bufB, Wt2, dinv, bufA, n);
    agg_fin_c<<<aggb, 256, 0, stream>>>((const uint4*)bufA, rowstart, rowend, colidx,
                                        dinv, b2, Wc, bc, out, n);
}

// Round 3
// 301.232 us; speedup vs baseline: 1.6093x; 1.6093x over previous
//
#include <hip/hip_runtime.h>
#include <hip/hip_bf16.h>

// GCN on MI355X. Pipeline (9 launches):
//   initcur + bin_edges (fixed-cap buckets) + build_rows : CSR by dst (ushort colidx)
//   prep_wt        : W1,W2 -> bf16 transposed [n][k] (MFMA B-operand layout)
//   gemm_mfma<f32> : h1' = dinv ⊙ (x@W1)             -> bufA (bf16, CHUNK-major)
//   agg_mid_c      : a1 = relu(di*(self+Σ h1') + b1)  -> bufB (bf16, CHUNK-major)
//   gemm_mfma<bf16>: h2' = dinv ⊙ (a1@W2)            -> bufA (bf16, CHUNK-major)
//   agg_fin_c      : a2 = relu(di*(self+Σ h2') + b2); f32 partial a2@Wc -> part[c]
//   reduce_out     : out = Σ_c part[c] + bc
//
// CHUNK-major h layout: H[c][node][32 feats] bf16, c in 0..3 -> 64B per entry.
// Aggregation is FEATURE-CHUNKED, tuned from round-2 evidence:
//  - 16B/8-chunk version: FETCH 160->21MB (L2-residency CONFIRMED) but L2->L1
//    line amplification (16B used per line) + 6.4M cross-XCD atomicAdds
//    (WRITE_SIZE 205MB partial-line HBM RMW) made it 3.5x slower.
//  - Now: 64B entries (4-lane coalesced quad per node), 4 chunks; per-chunk
//    working set 3.2MB fits 4MB per-XCD L2 (chunk f=blockIdx&3 -> XCDs {f,f+4}).
//    4x fewer L2 requests, >=50% line use. agg_fin writes PLAIN f32 partials
//    (no atomics); reduce_out sums them. colidx ushort (n <= 65536).
// Per node: 4 lanes; unmasked 8-edge main loop, one masked-8 tail iteration
// (dummy = self row, compensated analytically).
// GEMMs: mfma_f32_16x16x32_bf16, wave = 16 rows x 128 cols. Requires n <= 65536.

typedef unsigned int uint;
typedef unsigned short ushort;
typedef __attribute__((ext_vector_type(8))) short bf16x8;
typedef __attribute__((ext_vector_type(4))) float f32x4;

#define NPB 256
#define MAXBKT 256
#define CAP 12288   // edges per bucket region; mean 8192, sd ~90

static __device__ __forceinline__ ushort f2bf(float f) {
    unsigned u = __float_as_uint(f);
    u += 0x7fffu + ((u >> 16) & 1u);   // round-to-nearest-even
    return (ushort)(u >> 16);
}
static __device__ __forceinline__ uint pack2(float a, float b) {
    return (uint)f2bf(a) | ((uint)f2bf(b) << 16);
}
static __device__ __forceinline__ float lo2f(uint u) { return __uint_as_float(u << 16); }
static __device__ __forceinline__ float hi2f(uint u) { return __uint_as_float(u & 0xffff0000u); }

#define UNPACK8(dst, u)                                        \
    dst[0] = lo2f(u.x); dst[1] = hi2f(u.x);                    \
    dst[2] = lo2f(u.y); dst[3] = hi2f(u.y);                    \
    dst[4] = lo2f(u.z); dst[5] = hi2f(u.z);                    \
    dst[6] = lo2f(u.w); dst[7] = hi2f(u.w);

// ---------------- CSR build (fixed-capacity buckets) ----------------

__global__ __launch_bounds__(256) void initcur(int* __restrict__ bcursor, int nbuckets) {
    int t = threadIdx.x;
    if (t < nbuckets) bcursor[t] = t * CAP;
}

__global__ __launch_bounds__(256) void bin_edges(const int* __restrict__ src,
                                                 const int* __restrict__ dst,
                                                 int* __restrict__ bcursor,
                                                 uint* __restrict__ pay,
                                                 int E, int nbuckets) {
    __shared__ int h[MAXBKT];
    __shared__ int base[MAXBKT];
    int tid = threadIdx.x;
    h[tid] = 0;
    __syncthreads();
    int chunk = (E + gridDim.x - 1) / gridDim.x;
    int i0 = blockIdx.x * chunk;
    int i1 = min(E, i0 + chunk);
    for (int i = i0 + tid; i < i1; i += 256) atomicAdd(&h[dst[i] >> 8], 1);
    __syncthreads();
    if (tid < nbuckets) base[tid] = h[tid] ? atomicAdd(&bcursor[tid], h[tid]) : 0;
    __syncthreads();
    h[tid] = 0;
    __syncthreads();
    for (int i = i0 + tid; i < i1; i += 256) {
        int d = dst[i];
        int b = d >> 8;
        int pos = base[b] + atomicAdd(&h[b], 1);
        pay[pos] = (uint)src[i] | ((uint)(d & 255) << 24);
    }
}

__global__ __launch_bounds__(256) void build_rows(const uint* __restrict__ pay,
                                                  const int* __restrict__ bcursor,
                                                  int* __restrict__ rowstart,
                                                  int* __restrict__ rowend,
                                                  float* __restrict__ dinv,
                                                  ushort* __restrict__ colidx, int n) {
    __shared__ int hist[NPB];
    __shared__ int sc[NPB];
    __shared__ int cur[NPB];
    int tid = threadIdx.x;
    int b = blockIdx.x;
    int node0 = b * NPB;
    int s = b * CAP, e = bcursor[b];

    hist[tid] = 0;
    __syncthreads();
    for (int i = s + tid; i < e; i += 256) atomicAdd(&hist[pay[i] >> 24], 1);
    __syncthreads();

    int v = hist[tid];
    sc[tid] = v;
    __syncthreads();
    for (int d = 1; d < 256; d <<= 1) {
        int x = (tid >= d) ? sc[tid - d] : 0;
        __syncthreads();
        sc[tid] += x;
        __syncthreads();
    }
    int excl = sc[tid] - v;
    cur[tid] = s + excl;
    int node = node0 + tid;
    if (node < n) {
        rowstart[node] = s + excl;
        rowend[node] = s + excl + v;
        dinv[node] = rsqrtf((float)(v + 1));  // +1 self-loop
    }
    __syncthreads();

    for (int i = s + tid; i < e; i += 256) {
        uint p = pay[i];
        int pos = atomicAdd(&cur[p >> 24], 1);
        colidx[pos] = (ushort)p;   // src < 65536
    }
}

// ---------------- W prep: bf16 transpose [n][k] for MFMA B-operand ----------
__global__ __launch_bounds__(256) void prep_wt(const float* __restrict__ W1,
                                               const float* __restrict__ W2,
                                               ushort* __restrict__ Wt1,
                                               ushort* __restrict__ Wt2) {
    int idx = blockIdx.x * 256 + threadIdx.x;  // 0..16383
    int k = idx >> 7, nn = idx & 127;
    Wt1[nn * 128 + k] = f2bf(W1[idx]);
    Wt2[nn * 128 + k] = f2bf(W2[idx]);
}

// ------- MFMA GEMM: Y = dinv ⊙ (X @ W), bf16 packed, CHUNK-major output -------
// Block 256 = 4 waves; wave computes 16 rows x 128 cols.
// mfma_f32_16x16x32_bf16 layouts (verified learn_hip m89/m120):
//   A[m][k]: m=lane&15, k=quad*8+j    B[k][n]: n=lane&15, k=quad*8+j
//   C/D:     col=lane&15, row=quad*4+reg
// A (when bf16) read from chunk-major [c][node][32], c = ks, sub-granule = quad.
// Output written chunk-major: node entry = 64B (16 uints), sub-granule = 16B.
template <bool A_BF16>
__global__ __launch_bounds__(256) void gemm_mfma(const void* __restrict__ Xv,
                                                 const ushort* __restrict__ Wt,
                                                 const float* __restrict__ dinv,
                                                 uint* __restrict__ Yb, int n) {
    __shared__ __align__(16) ushort sOut[4][16][136];  // pad: 272B row stride
    const int wave = threadIdx.x >> 6;
    const int lane = threadIdx.x & 63;
    const int quad = lane >> 4, l16 = lane & 15;
    const int m0 = blockIdx.x * 64 + wave * 16;

    f32x4 acc[8];
#pragma unroll
    for (int t = 0; t < 8; ++t) acc[t] = (f32x4){0.f, 0.f, 0.f, 0.f};

    int arow = m0 + l16;
    arow = arow < n ? arow : n - 1;

#pragma unroll
    for (int ks = 0; ks < 4; ++ks) {
        bf16x8 a;
        if (A_BF16) {
            const ushort* X = (const ushort*)Xv;
            // chunk-major: chunk = ks, entry = 32 ushorts, sub-granule = quad
            a = *(const bf16x8*)&X[((size_t)ks * n + arow) * 32 + quad * 8];
        } else {
            const float* X = (const float*)Xv;
            const float* px = &X[(size_t)arow * 128 + ks * 32 + quad * 8];
            float4 x0 = *(const float4*)px;
            float4 x1 = *(const float4*)(px + 4);
            ushort av[8] = {f2bf(x0.x), f2bf(x0.y), f2bf(x0.z), f2bf(x0.w),
                            f2bf(x1.x), f2bf(x1.y), f2bf(x1.z), f2bf(x1.w)};
            a = *(const bf16x8*)av;
        }
#pragma unroll
        for (int nt = 0; nt < 8; ++nt) {
            bf16x8 b = *(const bf16x8*)&Wt[(size_t)(nt * 16 + l16) * 128 + ks * 32 + quad * 8];
            acc[nt] = __builtin_amdgcn_mfma_f32_16x16x32_bf16(a, b, acc[nt], 0, 0, 0);
        }
    }

    // epilogue: scale rows by dinv, pack bf16 into LDS, chunk-major store
    float dv[4];
#pragma unroll
    for (int r = 0; r < 4; ++r) {
        int rr = m0 + quad * 4 + r;
        dv[r] = dinv[rr < n ? rr : n - 1];
    }
#pragma unroll
    for (int nt = 0; nt < 8; ++nt)
#pragma unroll
        for (int r = 0; r < 4; ++r)
            sOut[wave][quad * 4 + r][nt * 16 + l16] = f2bf(acc[nt][r] * dv[r]);
    __syncthreads();

#pragma unroll
    for (int i = 0; i < 4; ++i) {
        int linear = i * 64 + lane;
        int g = linear >> 4, row = linear & 15;   // granule 0..15, 16 rows per group
        int rr = m0 + row;
        if (rr < n) {
            uint4 v = *(const uint4*)&sOut[wave][row][g * 8];
            // chunk c = g>>2, sub-granule = g&3; wave writes a contiguous 1KB span
            *(uint4*)&Yb[((size_t)(g >> 2) * n + rr) * 16 + (g & 3) * 4] = v;
        }
    }
}

// ------------- aggregate core: one node per LANE QUAD, one 32-feature chunk -------------
// Hc4: uint4 view of chunk-major h buffer. Lane handles sub-granule sub (8 feats);
// entry index for node v = cbase + v*4, cbase = (size_t)c*n*4 + sub.
// Unmasked 8-edge main loop (8 loads in flight), one masked-8 tail iteration
// with dummy = self row (L2-hot) compensated by acc -= pad * t.
static __device__ __forceinline__ void gather_c(const uint4* __restrict__ Hc4,
                                                int s, int e, int nn, size_t cbase,
                                                const ushort* __restrict__ colidx,
                                                float acc[8]) {
    uint4 su = Hc4[cbase + (size_t)nn * 4];
    float t[8];
    UNPACK8(t, su);
#pragma unroll
    for (int j = 0; j < 8; ++j) acc[j] = t[j];   // self term (pre-scaled h')

    int p = s;
    for (; p + 8 <= e; p += 8) {
        int c[8];
#pragma unroll
        for (int i = 0; i < 8; ++i) c[i] = colidx[p + i];
        uint4 u[8];
#pragma unroll
        for (int i = 0; i < 8; ++i) u[i] = Hc4[cbase + (size_t)c[i] * 4];
#pragma unroll
        for (int i = 0; i < 8; ++i) {
            float a[8];
            UNPACK8(a, u[i]);
#pragma unroll
            for (int j = 0; j < 8; ++j) acc[j] += a[j];
        }
    }
    if (p < e) {
        int c[8];
#pragma unroll
        for (int i = 0; i < 8; ++i) c[i] = (p + i < e) ? (int)colidx[p + i] : nn;
        uint4 u[8];
#pragma unroll
        for (int i = 0; i < 8; ++i) u[i] = Hc4[cbase + (size_t)c[i] * 4];
#pragma unroll
        for (int i = 0; i < 8; ++i) {
            float a[8];
            UNPACK8(a, u[i]);
#pragma unroll
            for (int j = 0; j < 8; ++j) acc[j] += a[j];
        }
        float pad = (float)(p + 8 - e);   // dummies added self row 'pad' times
#pragma unroll
        for (int j = 0; j < 8; ++j) acc[j] -= pad * t[j];
    }
}

// middle layer: a1 = relu(di*sum + b1), bf16 chunk-major. chunk f = blockIdx&3
// (-> XCDs {f, f+4} under round-robin dispatch), 64 nodes/block, 4 lanes/node.
__global__ __launch_bounds__(256) void agg_mid_c(const uint4* __restrict__ Hc4,
                                                 const int* __restrict__ rowstart,
                                                 const int* __restrict__ rowend,
                                                 const ushort* __restrict__ colidx,
                                                 const float* __restrict__ dinv,
                                                 const float* __restrict__ bias,
                                                 uint4* __restrict__ Oc4, int n) {
    int tid = threadIdx.x;
    int sub = tid & 3;
    int f = blockIdx.x & 3;
    int node = (blockIdx.x >> 2) * 64 + (tid >> 2);
    int nn = node < n ? node : n - 1;
    int s = rowstart[nn], e = rowend[nn];
    float di = dinv[nn];
    size_t cbase = (size_t)f * n * 4 + sub;

    float acc[8];
    gather_c(Hc4, s, e, nn, cbase, colidx, acc);

    if (node < n) {
        int gid = f * 4 + sub;                    // granule 0..15 (feats gid*8..+7)
        const float4* B4 = (const float4*)bias;
        float4 b0 = B4[gid * 2];
        float4 b1 = B4[gid * 2 + 1];
        float o0 = fmaxf(fmaf(acc[0], di, b0.x), 0.f);
        float o1 = fmaxf(fmaf(acc[1], di, b0.y), 0.f);
        float o2 = fmaxf(fmaf(acc[2], di, b0.z), 0.f);
        float o3 = fmaxf(fmaf(acc[3], di, b0.w), 0.f);
        float o4 = fmaxf(fmaf(acc[4], di, b1.x), 0.f);
        float o5 = fmaxf(fmaf(acc[5], di, b1.y), 0.f);
        float o6 = fmaxf(fmaf(acc[6], di, b1.z), 0.f);
        float o7 = fmaxf(fmaf(acc[7], di, b1.w), 0.f);
        uint4 ov;
        ov.x = pack2(o0, o1); ov.y = pack2(o2, o3);
        ov.z = pack2(o4, o5); ov.w = pack2(o6, o7);
        Oc4[cbase + (size_t)node * 4] = ov;
    }
}

// final layer + classifier partial: a2 stays f32 in registers; chunk computes
// its 32-row slice of a2@Wc (quad-reduced) and writes f32 partials (NO atomics).
__global__ __launch_bounds__(256) void agg_fin_c(const uint4* __restrict__ Hc4,
                                                 const int* __restrict__ rowstart,
                                                 const int* __restrict__ rowend,
                                                 const ushort* __restrict__ colidx,
                                                 const float* __restrict__ dinv,
                                                 const float* __restrict__ bias,
                                                 const float* __restrict__ Wc,
                                                 float4* __restrict__ part4, int n) {
    int tid = threadIdx.x;
    int sub = tid & 3;
    int f = blockIdx.x & 3;
    int node = (blockIdx.x >> 2) * 64 + (tid >> 2);
    int nn = node < n ? node : n - 1;
    int s = rowstart[nn], e = rowend[nn];
    float di = dinv[nn];
    size_t cbase = (size_t)f * n * 4 + sub;

    float acc[8];
    gather_c(Hc4, s, e, nn, cbase, colidx, acc);

    int gid = f * 4 + sub;
    float a[8];
    {
        const float4* B4 = (const float4*)bias;
        float4 b0 = B4[gid * 2];
        float4 b1 = B4[gid * 2 + 1];
        a[0] = fmaxf(fmaf(acc[0], di, b0.x), 0.f);
        a[1] = fmaxf(fmaf(acc[1], di, b0.y), 0.f);
        a[2] = fmaxf(fmaf(acc[2], di, b0.z), 0.f);
        a[3] = fmaxf(fmaf(acc[3], di, b0.w), 0.f);
        a[4] = fmaxf(fmaf(acc[4], di, b1.x), 0.f);
        a[5] = fmaxf(fmaf(acc[5], di, b1.y), 0.f);
        a[6] = fmaxf(fmaf(acc[6], di, b1.z), 0.f);
        a[7] = fmaxf(fmaf(acc[7], di, b1.w), 0.f);
    }

    // partial dot: this lane covers Wc rows gid*8 .. gid*8+7 (L1-broadcast loads)
    float p[16];
#pragma unroll
    for (int c = 0; c < 16; ++c) p[c] = 0.f;
#pragma unroll
    for (int j = 0; j < 8; ++j) {
        const float4* wr = (const float4*)&Wc[(size_t)(gid * 8 + j) * 16];
        float4 w0 = wr[0], w1 = wr[1], w2 = wr[2], w3 = wr[3];
        float aj = a[j];
        p[0]  = fmaf(aj, w0.x, p[0]);  p[1]  = fmaf(aj, w0.y, p[1]);
        p[2]  = fmaf(aj, w0.z, p[2]);  p[3]  = fmaf(aj, w0.w, p[3]);
        p[4]  = fmaf(aj, w1.x, p[4]);  p[5]  = fmaf(aj, w1.y, p[5]);
        p[6]  = fmaf(aj, w1.z, p[6]);  p[7]  = fmaf(aj, w1.w, p[7]);
        p[8]  = fmaf(aj, w2.x, p[8]);  p[9]  = fmaf(aj, w2.y, p[9]);
        p[10] = fmaf(aj, w2.z, p[10]); p[11] = fmaf(aj, w2.w, p[11]);
        p[12] = fmaf(aj, w3.x, p[12]); p[13] = fmaf(aj, w3.y, p[13]);
        p[14] = fmaf(aj, w3.z, p[14]); p[15] = fmaf(aj, w3.w, p[15]);
    }
    // reduce across the 4-lane quad (feats f*32..f*32+31)
#pragma unroll
    for (int c = 0; c < 16; ++c) {
        p[c] += __shfl_xor(p[c], 1);
        p[c] += __shfl_xor(p[c], 2);
    }

    if (node < n) {
        // lane sub writes cols sub*4..sub*4+3; quad writes 64B coalesced
        float4 v = {p[sub * 4], p[sub * 4 + 1], p[sub * 4 + 2], p[sub * 4 + 3]};
        part4[cbase + (size_t)node * 4] = v;
    }
}

// out[node][16] = sum_c part[c][node][16] + bc
__global__ __launch_bounds__(256) void reduce_out(const float4* __restrict__ part4,
                                                  const float* __restrict__ bc,
                                                  float4* __restrict__ out4, int n) {
    int i = blockIdx.x * 256 + threadIdx.x;     // one float4 (4 cols) per thread
    int total = n * 4;
    if (i >= total) return;
    int q = i & 3;
    float4 b = ((const float4*)bc)[q];
    float4 s0 = part4[i];
    float4 s1 = part4[(size_t)n * 4 + i];
    float4 s2 = part4[(size_t)n * 8 + i];
    float4 s3 = part4[(size_t)n * 12 + i];
    float4 r;
    r.x = s0.x + s1.x + s2.x + s3.x + b.x;
    r.y = s0.y + s1.y + s2.y + s3.y + b.y;
    r.z = s0.z + s1.z + s2.z + s3.z + b.z;
    r.w = s0.w + s1.w + s2.w + s3.w + b.w;
    out4[i] = r;
}

// ---------------- launch ----------------

extern "C" void kernel_launch(void* const* d_in, const int* in_sizes, int n_in,
                              void* d_out, int out_size, void* d_ws, size_t ws_size,
                              hipStream_t stream) {
    const float* x  = (const float*)d_in[0];
    const int*   ei = (const int*)d_in[1];
    const float* W1 = (const float*)d_in[2];
    const float* b1 = (const float*)d_in[3];
    const float* W2 = (const float*)d_in[4];
    const float* b2 = (const float*)d_in[5];
    const float* Wc = (const float*)d_in[6];
    const float* bc = (const float*)d_in[7];
    float* out = (float*)d_out;

    const int n = in_sizes[0] / 128;  // 50000
    const int E = in_sizes[1] / 2;    // 1,600,000
    const int* src = ei;
    const int* dst = ei + E;
    const int nbuckets = (n + NPB - 1) / NPB;  // 196

    char* p = (char*)d_ws;
    auto alloc = [&](size_t bytes) {
        char* q = p;
        p += (bytes + 255) & ~(size_t)255;
        return q;
    };
    int*    bcursor  = (int*)alloc(MAXBKT * 4);
    int*    rowstart = (int*)alloc((size_t)n * 4);
    int*    rowend   = (int*)alloc((size_t)n * 4);
    float*  dinv     = (float*)alloc((size_t)n * 4);
    ushort* Wt1      = (ushort*)alloc(128 * 128 * 2);
    ushort* Wt2      = (ushort*)alloc(128 * 128 * 2);
    uint*   pay      = (uint*)alloc((size_t)nbuckets * CAP * 4);
    ushort* colidx   = (ushort*)alloc((size_t)nbuckets * CAP * 2);
    uint*   bufA     = (uint*)alloc((size_t)n * 64 * 4);   // bf16 h' (chunk-major)
    uint*   bufB     = (uint*)alloc((size_t)n * 64 * 4);   // bf16 a1 (chunk-major)
    float*  part     = (float*)alloc((size_t)n * 64 * 4);  // f32 partials [4][n][16]
    if ((size_t)(p - (char*)d_ws) > ws_size) return;

    initcur<<<1, 256, 0, stream>>>(bcursor, nbuckets);
    bin_edges<<<256, 256, 0, stream>>>(src, dst, bcursor, pay, E, nbuckets);
    build_rows<<<nbuckets, 256, 0, stream>>>(pay, bcursor, rowstart, rowend, dinv, colidx, n);
    prep_wt<<<64, 256, 0, stream>>>(W1, W2, Wt1, Wt2);

    const int gemmb = (n + 63) / 64;
    const int aggb = 4 * ((n + 63) / 64);   // 4 feature chunks x node blocks
    const int redb = (n * 4 + 255) / 256;
    gemm_mfma<false><<<gemmb, 256, 0, stream>>>(x, Wt1, dinv, bufA, n);
    agg_mid_c<<<aggb, 256, 0, stream>>>((const uint4*)bufA, rowstart, rowend, colidx,
                                        dinv, b1, (uint4*)bufB, n);
    gemm_mfma<true><<<gemmb, 256, 0, stream>>>(bufB, Wt2, dinv, bufA, n);
    agg_fin_c<<<aggb, 256, 0, stream>>>((const uint4*)bufA, rowstart, rowend, colidx,
                                        dinv, b2, Wc, (float4*)part, n);
    reduce_out<<<redb, 256, 0, stream>>>((const float4*)part, bc, (float4*)out, n);
}

// Round 4
// 295.506 us; speedup vs baseline: 1.6405x; 1.0194x over previous
//
#include <hip/hip_runtime.h>
#include <hip/hip_bf16.h>

// GCN on MI355X. Pipeline (9 launches):
//   initcur + bin_edges (fixed-cap buckets) + build_rows : CSR by dst (ushort colidx)
//   prep_wt        : W1,W2 -> bf16 transposed [n][k] (MFMA B-operand layout)
//   gemm_mfma<f32> : h1' = dinv ⊙ (x@W1)             -> bufA (bf16, 2-CHUNK-major)
//   agg_mid_c      : a1 = relu(di*(self+Σ h1') + b1)  -> bufB (bf16, 2-CHUNK-major)
//   gemm_mfma<bf16>: h2' = dinv ⊙ (a1@W2)            -> bufA (bf16, 2-CHUNK-major)
//   agg_fin_c      : a2 = relu(di*(self+Σ h2') + b2); f32 partial a2@Wc -> part[c]
//   reduce_out     : out = Σ_c part[c] + bc
//
// CHUNK-major h layout: H[c][node][64 feats] bf16, c in 0..1 -> 128B per entry
// = EXACTLY ONE CACHE LINE. Evidence across rounds: agg time is monotone in
// distinct line-requests (~13-18us per M): full-row 3.2M->58us, 64B-chunk
// 6.4M->84us, 16B-chunk 12.8M->~200us; bytes/HBM don't matter (request-rate
// bound at TA/TCP). This version returns to the 3.2M floor (1 line per
// edge-chunk, 100% line use) AND keeps L2 residency: chunk f = blockIdx&1
// -> XCD parity set {0,2,4,6}/{1,3,5,7} under %8 round-robin; 6.4MB/chunk
// across 4 XCDs. No atomics (round-2 lesson): agg_fin writes f32 partials,
// reduce_out sums. colidx ushort (n <= 65536).
// Per node: 8 lanes (8 x 16B = one line); unmasked 8-edge main loop (8 lines
// in flight/lane-group), one masked-8 tail (dummy = self row, compensated).
// GEMMs: mfma_f32_16x16x32_bf16, wave = 16 rows x 128 cols. Requires n <= 65536.

typedef unsigned int uint;
typedef unsigned short ushort;
typedef __attribute__((ext_vector_type(8))) short bf16x8;
typedef __attribute__((ext_vector_type(4))) float f32x4;

#define NPB 256
#define MAXBKT 256
#define CAP 12288   // edges per bucket region; mean 8192, sd ~90

static __device__ __forceinline__ ushort f2bf(float f) {
    unsigned u = __float_as_uint(f);
    u += 0x7fffu + ((u >> 16) & 1u);   // round-to-nearest-even
    return (ushort)(u >> 16);
}
static __device__ __forceinline__ uint pack2(float a, float b) {
    return (uint)f2bf(a) | ((uint)f2bf(b) << 16);
}
static __device__ __forceinline__ float lo2f(uint u) { return __uint_as_float(u << 16); }
static __device__ __forceinline__ float hi2f(uint u) { return __uint_as_float(u & 0xffff0000u); }

#define UNPACK8(dst, u)                                        \
    dst[0] = lo2f(u.x); dst[1] = hi2f(u.x);                    \
    dst[2] = lo2f(u.y); dst[3] = hi2f(u.y);                    \
    dst[4] = lo2f(u.z); dst[5] = hi2f(u.z);                    \
    dst[6] = lo2f(u.w); dst[7] = hi2f(u.w);

// ---------------- CSR build (fixed-capacity buckets) ----------------

__global__ __launch_bounds__(256) void initcur(int* __restrict__ bcursor, int nbuckets) {
    int t = threadIdx.x;
    if (t < nbuckets) bcursor[t] = t * CAP;
}

__global__ __launch_bounds__(256) void bin_edges(const int* __restrict__ src,
                                                 const int* __restrict__ dst,
                                                 int* __restrict__ bcursor,
                                                 uint* __restrict__ pay,
                                                 int E, int nbuckets) {
    __shared__ int h[MAXBKT];
    __shared__ int base[MAXBKT];
    int tid = threadIdx.x;
    h[tid] = 0;
    __syncthreads();
    int chunk = (E + gridDim.x - 1) / gridDim.x;
    int i0 = blockIdx.x * chunk;
    int i1 = min(E, i0 + chunk);
    for (int i = i0 + tid; i < i1; i += 256) atomicAdd(&h[dst[i] >> 8], 1);
    __syncthreads();
    if (tid < nbuckets) base[tid] = h[tid] ? atomicAdd(&bcursor[tid], h[tid]) : 0;
    __syncthreads();
    h[tid] = 0;
    __syncthreads();
    for (int i = i0 + tid; i < i1; i += 256) {
        int d = dst[i];
        int b = d >> 8;
        int pos = base[b] + atomicAdd(&h[b], 1);
        pay[pos] = (uint)src[i] | ((uint)(d & 255) << 24);
    }
}

__global__ __launch_bounds__(256) void build_rows(const uint* __restrict__ pay,
                                                  const int* __restrict__ bcursor,
                                                  int* __restrict__ rowstart,
                                                  int* __restrict__ rowend,
                                                  float* __restrict__ dinv,
                                                  ushort* __restrict__ colidx, int n) {
    __shared__ int hist[NPB];
    __shared__ int sc[NPB];
    __shared__ int cur[NPB];
    int tid = threadIdx.x;
    int b = blockIdx.x;
    int node0 = b * NPB;
    int s = b * CAP, e = bcursor[b];

    hist[tid] = 0;
    __syncthreads();
    for (int i = s + tid; i < e; i += 256) atomicAdd(&hist[pay[i] >> 24], 1);
    __syncthreads();

    int v = hist[tid];
    sc[tid] = v;
    __syncthreads();
    for (int d = 1; d < 256; d <<= 1) {
        int x = (tid >= d) ? sc[tid - d] : 0;
        __syncthreads();
        sc[tid] += x;
        __syncthreads();
    }
    int excl = sc[tid] - v;
    cur[tid] = s + excl;
    int node = node0 + tid;
    if (node < n) {
        rowstart[node] = s + excl;
        rowend[node] = s + excl + v;
        dinv[node] = rsqrtf((float)(v + 1));  // +1 self-loop
    }
    __syncthreads();

    for (int i = s + tid; i < e; i += 256) {
        uint p = pay[i];
        int pos = atomicAdd(&cur[p >> 24], 1);
        colidx[pos] = (ushort)p;   // src < 65536
    }
}

// ---------------- W prep: bf16 transpose [n][k] for MFMA B-operand ----------
__global__ __launch_bounds__(256) void prep_wt(const float* __restrict__ W1,
                                               const float* __restrict__ W2,
                                               ushort* __restrict__ Wt1,
                                               ushort* __restrict__ Wt2) {
    int idx = blockIdx.x * 256 + threadIdx.x;  // 0..16383
    int k = idx >> 7, nn = idx & 127;
    Wt1[nn * 128 + k] = f2bf(W1[idx]);
    Wt2[nn * 128 + k] = f2bf(W2[idx]);
}

// ------- MFMA GEMM: Y = dinv ⊙ (X @ W), bf16 packed, 2-CHUNK-major output -------
// Block 256 = 4 waves; wave computes 16 rows x 128 cols.
// mfma_f32_16x16x32_bf16 layouts (verified learn_hip m89/m120):
//   A[m][k]: m=lane&15, k=quad*8+j    B[k][n]: n=lane&15, k=quad*8+j
//   C/D:     col=lane&15, row=quad*4+reg
// A (when bf16) read from chunk-major [c][node][64]: c = ks>>1,
// in-entry granule = (ks&1)*4+quad. Output entry = 128B (32 uints).
template <bool A_BF16>
__global__ __launch_bounds__(256) void gemm_mfma(const void* __restrict__ Xv,
                                                 const ushort* __restrict__ Wt,
                                                 const float* __restrict__ dinv,
                                                 uint* __restrict__ Yb, int n) {
    __shared__ __align__(16) ushort sOut[4][16][136];  // pad: 272B row stride
    const int wave = threadIdx.x >> 6;
    const int lane = threadIdx.x & 63;
    const int quad = lane >> 4, l16 = lane & 15;
    const int m0 = blockIdx.x * 64 + wave * 16;

    f32x4 acc[8];
#pragma unroll
    for (int t = 0; t < 8; ++t) acc[t] = (f32x4){0.f, 0.f, 0.f, 0.f};

    int arow = m0 + l16;
    arow = arow < n ? arow : n - 1;

#pragma unroll
    for (int ks = 0; ks < 4; ++ks) {
        bf16x8 a;
        if (A_BF16) {
            const ushort* X = (const ushort*)Xv;
            // chunk-major: chunk = ks>>1, entry = 64 ushorts, granule = (ks&1)*4+quad
            a = *(const bf16x8*)&X[((size_t)(ks >> 1) * n + arow) * 64 +
                                   ((ks & 1) * 4 + quad) * 8];
        } else {
            const float* X = (const float*)Xv;
            const float* px = &X[(size_t)arow * 128 + ks * 32 + quad * 8];
            float4 x0 = *(const float4*)px;
            float4 x1 = *(const float4*)(px + 4);
            ushort av[8] = {f2bf(x0.x), f2bf(x0.y), f2bf(x0.z), f2bf(x0.w),
                            f2bf(x1.x), f2bf(x1.y), f2bf(x1.z), f2bf(x1.w)};
            a = *(const bf16x8*)av;
        }
#pragma unroll
        for (int nt = 0; nt < 8; ++nt) {
            bf16x8 b = *(const bf16x8*)&Wt[(size_t)(nt * 16 + l16) * 128 + ks * 32 + quad * 8];
            acc[nt] = __builtin_amdgcn_mfma_f32_16x16x32_bf16(a, b, acc[nt], 0, 0, 0);
        }
    }

    // epilogue: scale rows by dinv, pack bf16 into LDS, chunk-major store
    float dv[4];
#pragma unroll
    for (int r = 0; r < 4; ++r) {
        int rr = m0 + quad * 4 + r;
        dv[r] = dinv[rr < n ? rr : n - 1];
    }
#pragma unroll
    for (int nt = 0; nt < 8; ++nt)
#pragma unroll
        for (int r = 0; r < 4; ++r)
            sOut[wave][quad * 4 + r][nt * 16 + l16] = f2bf(acc[nt][r] * dv[r]);
    __syncthreads();

#pragma unroll
    for (int i = 0; i < 4; ++i) {
        int linear = i * 64 + lane;
        int g = linear >> 4, row = linear & 15;   // granule 0..15, 16 rows per group
        int rr = m0 + row;
        if (rr < n) {
            uint4 v = *(const uint4*)&sOut[wave][row][g * 8];
            // chunk c = g>>3, in-entry uint4 slot = g&7 (entry = 32 uints = 128B)
            *(uint4*)&Yb[((size_t)(g >> 3) * n + rr) * 32 + (g & 7) * 4] = v;
        }
    }
}

// ---- aggregate core: one node per 8-LANE GROUP, one 64-feature chunk (1 line) ----
// Hc4: uint4 view of chunk-major h buffer. Lane handles in-entry slot sub (8 feats);
// entry for node v at uint4 index cbase + v*8, cbase = (size_t)c*n*8 + sub.
// Unmasked 8-edge main loop (8 lines in flight), one masked-8 tail iteration
// with dummy = self row (cache-hot) compensated by acc -= pad * t.
static __device__ __forceinline__ void gather_c(const uint4* __restrict__ Hc4,
                                                int s, int e, int nn, size_t cbase,
                                                const ushort* __restrict__ colidx,
                                                float acc[8]) {
    uint4 su = Hc4[cbase + (size_t)nn * 8];
    float t[8];
    UNPACK8(t, su);
#pragma unroll
    for (int j = 0; j < 8; ++j) acc[j] = t[j];   // self term (pre-scaled h')

    int p = s;
    for (; p + 8 <= e; p += 8) {
        int c[8];
#pragma unroll
        for (int i = 0; i < 8; ++i) c[i] = colidx[p + i];
        uint4 u[8];
#pragma unroll
        for (int i = 0; i < 8; ++i) u[i] = Hc4[cbase + (size_t)c[i] * 8];
#pragma unroll
        for (int i = 0; i < 8; ++i) {
            float a[8];
            UNPACK8(a, u[i]);
#pragma unroll
            for (int j = 0; j < 8; ++j) acc[j] += a[j];
        }
    }
    if (p < e) {
        int c[8];
#pragma unroll
        for (int i = 0; i < 8; ++i) c[i] = (p + i < e) ? (int)colidx[p + i] : nn;
        uint4 u[8];
#pragma unroll
        for (int i = 0; i < 8; ++i) u[i] = Hc4[cbase + (size_t)c[i] * 8];
#pragma unroll
        for (int i = 0; i < 8; ++i) {
            float a[8];
            UNPACK8(a, u[i]);
#pragma unroll
            for (int j = 0; j < 8; ++j) acc[j] += a[j];
        }
        float pad = (float)(p + 8 - e);   // dummies added self row 'pad' times
#pragma unroll
        for (int j = 0; j < 8; ++j) acc[j] -= pad * t[j];
    }
}

// middle layer: a1 = relu(di*sum + b1), bf16 chunk-major. chunk f = blockIdx&1
// (-> XCD parity set under %8 round-robin), 32 nodes/block, 8 lanes/node.
__global__ __launch_bounds__(256) void agg_mid_c(const uint4* __restrict__ Hc4,
                                                 const int* __restrict__ rowstart,
                                                 const int* __restrict__ rowend,
                                                 const ushort* __restrict__ colidx,
                                                 const float* __restrict__ dinv,
                                                 const float* __restrict__ bias,
                                                 uint4* __restrict__ Oc4, int n) {
    int tid = threadIdx.x;
    int sub = tid & 7;
    int f = blockIdx.x & 1;
    int node = (blockIdx.x >> 1) * 32 + (tid >> 3);
    int nn = node < n ? node : n - 1;
    int s = rowstart[nn], e = rowend[nn];
    float di = dinv[nn];
    size_t cbase = (size_t)f * n * 8 + sub;

    float acc[8];
    gather_c(Hc4, s, e, nn, cbase, colidx, acc);

    if (node < n) {
        int gid = f * 8 + sub;                    // granule 0..15 (feats gid*8..+7)
        const float4* B4 = (const float4*)bias;
        float4 b0 = B4[gid * 2];
        float4 b1 = B4[gid * 2 + 1];
        float o0 = fmaxf(fmaf(acc[0], di, b0.x), 0.f);
        float o1 = fmaxf(fmaf(acc[1], di, b0.y), 0.f);
        float o2 = fmaxf(fmaf(acc[2], di, b0.z), 0.f);
        float o3 = fmaxf(fmaf(acc[3], di, b0.w), 0.f);
        float o4 = fmaxf(fmaf(acc[4], di, b1.x), 0.f);
        float o5 = fmaxf(fmaf(acc[5], di, b1.y), 0.f);
        float o6 = fmaxf(fmaf(acc[6], di, b1.z), 0.f);
        float o7 = fmaxf(fmaf(acc[7], di, b1.w), 0.f);
        uint4 ov;
        ov.x = pack2(o0, o1); ov.y = pack2(o2, o3);
        ov.z = pack2(o4, o5); ov.w = pack2(o6, o7);
        Oc4[cbase + (size_t)node * 8] = ov;
    }
}

// final layer + classifier partial: a2 stays f32 in registers; chunk computes
// its 64-row slice of a2@Wc (8-lane reduced) and writes f32 partials (NO atomics).
__global__ __launch_bounds__(256) void agg_fin_c(const uint4* __restrict__ Hc4,
                                                 const int* __restrict__ rowstart,
                                                 const int* __restrict__ rowend,
                                                 const ushort* __restrict__ colidx,
                                                 const float* __restrict__ dinv,
                                                 const float* __restrict__ bias,
                                                 const float* __restrict__ Wc,
                                                 float4* __restrict__ part4, int n) {
    int tid = threadIdx.x;
    int sub = tid & 7;
    int f = blockIdx.x & 1;
    int node = (blockIdx.x >> 1) * 32 + (tid >> 3);
    int nn = node < n ? node : n - 1;
    int s = rowstart[nn], e = rowend[nn];
    float di = dinv[nn];
    size_t cbase = (size_t)f * n * 8 + sub;

    float acc[8];
    gather_c(Hc4, s, e, nn, cbase, colidx, acc);

    int gid = f * 8 + sub;
    float a[8];
    {
        const float4* B4 = (const float4*)bias;
        float4 b0 = B4[gid * 2];
        float4 b1 = B4[gid * 2 + 1];
        a[0] = fmaxf(fmaf(acc[0], di, b0.x), 0.f);
        a[1] = fmaxf(fmaf(acc[1], di, b0.y), 0.f);
        a[2] = fmaxf(fmaf(acc[2], di, b0.z), 0.f);
        a[3] = fmaxf(fmaf(acc[3], di, b0.w), 0.f);
        a[4] = fmaxf(fmaf(acc[4], di, b1.x), 0.f);
        a[5] = fmaxf(fmaf(acc[5], di, b1.y), 0.f);
        a[6] = fmaxf(fmaf(acc[6], di, b1.z), 0.f);
        a[7] = fmaxf(fmaf(acc[7], di, b1.w), 0.f);
    }

    // partial dot: this lane covers Wc rows gid*8 .. gid*8+7 (L1-broadcast loads)
    float p[16];
#pragma unroll
    for (int c = 0; c < 16; ++c) p[c] = 0.f;
#pragma unroll
    for (int j = 0; j < 8; ++j) {
        const float4* wr = (const float4*)&Wc[(size_t)(gid * 8 + j) * 16];
        float4 w0 = wr[0], w1 = wr[1], w2 = wr[2], w3 = wr[3];
        float aj = a[j];
        p[0]  = fmaf(aj, w0.x, p[0]);  p[1]  = fmaf(aj, w0.y, p[1]);
        p[2]  = fmaf(aj, w0.z, p[2]);  p[3]  = fmaf(aj, w0.w, p[3]);
        p[4]  = fmaf(aj, w1.x, p[4]);  p[5]  = fmaf(aj, w1.y, p[5]);
        p[6]  = fmaf(aj, w1.z, p[6]);  p[7]  = fmaf(aj, w1.w, p[7]);
        p[8]  = fmaf(aj, w2.x, p[8]);  p[9]  = fmaf(aj, w2.y, p[9]);
        p[10] = fmaf(aj, w2.z, p[10]); p[11] = fmaf(aj, w2.w, p[11]);
        p[12] = fmaf(aj, w3.x, p[12]); p[13] = fmaf(aj, w3.y, p[13]);
        p[14] = fmaf(aj, w3.z, p[14]); p[15] = fmaf(aj, w3.w, p[15]);
    }
    // reduce across the 8-lane group (feats f*64..f*64+63)
#pragma unroll
    for (int c = 0; c < 16; ++c) {
        p[c] += __shfl_xor(p[c], 1);
        p[c] += __shfl_xor(p[c], 2);
        p[c] += __shfl_xor(p[c], 4);
    }

    if (node < n && sub < 4) {
        // lanes 0..3 write cols sub*4..sub*4+3; 64B coalesced per node
        float4 v = {p[sub * 4], p[sub * 4 + 1], p[sub * 4 + 2], p[sub * 4 + 3]};
        part4[((size_t)f * n + node) * 4 + sub] = v;
    }
}

// out[node][16] = part[0][node][16] + part[1][node][16] + bc
__global__ __launch_bounds__(256) void reduce_out(const float4* __restrict__ part4,
                                                  const float* __restrict__ bc,
                                                  float4* __restrict__ out4, int n) {
    int i = blockIdx.x * 256 + threadIdx.x;     // one float4 (4 cols) per thread
    int total = n * 4;
    if (i >= total) return;
    int q = i & 3;
    float4 b = ((const float4*)bc)[q];
    float4 s0 = part4[i];
    float4 s1 = part4[(size_t)n * 4 + i];
    float4 r;
    r.x = s0.x + s1.x + b.x;
    r.y = s0.y + s1.y + b.y;
    r.z = s0.z + s1.z + b.z;
    r.w = s0.w + s1.w + b.w;
    out4[i] = r;
}

// ---------------- launch ----------------

extern "C" void kernel_launch(void* const* d_in, const int* in_sizes, int n_in,
                              void* d_out, int out_size, void* d_ws, size_t ws_size,
                              hipStream_t stream) {
    const float* x  = (const float*)d_in[0];
    const int*   ei = (const int*)d_in[1];
    const float* W1 = (const float*)d_in[2];
    const float* b1 = (const float*)d_in[3];
    const float* W2 = (const float*)d_in[4];
    const float* b2 = (const float*)d_in[5];
    const float* Wc = (const float*)d_in[6];
    const float* bc = (const float*)d_in[7];
    float* out = (float*)d_out;

    const int n = in_sizes[0] / 128;  // 50000
    const int E = in_sizes[1] / 2;    // 1,600,000
    const int* src = ei;
    const int* dst = ei + E;
    const int nbuckets = (n + NPB - 1) / NPB;  // 196

    char* p = (char*)d_ws;
    auto alloc = [&](size_t bytes) {
        char* q = p;
        p += (bytes + 255) & ~(size_t)255;
        return q;
    };
    int*    bcursor  = (int*)alloc(MAXBKT * 4);
    int*    rowstart = (int*)alloc((size_t)n * 4);
    int*    rowend   = (int*)alloc((size_t)n * 4);
    float*  dinv     = (float*)alloc((size_t)n * 4);
    ushort* Wt1      = (ushort*)alloc(128 * 128 * 2);
    ushort* Wt2      = (ushort*)alloc(128 * 128 * 2);
    uint*   pay      = (uint*)alloc((size_t)nbuckets * CAP * 4);
    ushort* colidx   = (ushort*)alloc((size_t)nbuckets * CAP * 2);
    uint*   bufA     = (uint*)alloc((size_t)n * 64 * 4);   // bf16 h' (chunk-major)
    uint*   bufB     = (uint*)alloc((size_t)n * 64 * 4);   // bf16 a1 (chunk-major)
    float*  part     = (float*)alloc((size_t)n * 32 * 4);  // f32 partials [2][n][16]
    if ((size_t)(p - (char*)d_ws) > ws_size) return;

    initcur<<<1, 256, 0, stream>>>(bcursor, nbuckets);
    bin_edges<<<256, 256, 0, stream>>>(src, dst, bcursor, pay, E, nbuckets);
    build_rows<<<nbuckets, 256, 0, stream>>>(pay, bcursor, rowstart, rowend, dinv, colidx, n);
    prep_wt<<<64, 256, 0, stream>>>(W1, W2, Wt1, Wt2);

    const int gemmb = (n + 63) / 64;
    const int aggb = 2 * ((n + 31) / 32);   // 2 feature chunks x node blocks
    const int redb = (n * 4 + 255) / 256;
    gemm_mfma<false><<<gemmb, 256, 0, stream>>>(x, Wt1, dinv, bufA, n);
    agg_mid_c<<<aggb, 256, 0, stream>>>((const uint4*)bufA, rowstart, rowend, colidx,
                                        dinv, b1, (uint4*)bufB, n);
    gemm_mfma<true><<<gemmb, 256, 0, stream>>>(bufB, Wt2, dinv, bufA, n);
    agg_fin_c<<<aggb, 256, 0, stream>>>((const uint4*)bufA, rowstart, rowend, colidx,
                                        dinv, b2, Wc, (float4*)part, n);
    reduce_out<<<redb, 256, 0, stream>>>((const float4*)part, bc, (float4*)out, n);
}

// Round 8
// 284.666 us; speedup vs baseline: 1.7029x; 1.0381x over previous
//
#include <hip/hip_runtime.h>
#include <hip/hip_bf16.h>

// GCN on MI355X. Pipeline (8 launches):
//   initcur + bin_edges (fixed-cap buckets) + build_rows : CSR by dst (ushort colidx)
//   prep_wt        : W1,W2 -> bf16 transposed [n][k] (MFMA B-operand layout)
//   gemm_mfma<f32> : h1' = dinv ⊙ (x@W1)             -> bufA (bf16, row-major)
//   agg_mid_q      : a1 = relu(di*(self+Σ h1') + b1)  -> bufB (bf16)
//   gemm_mfma<bf16>: h2' = dinv ⊙ (a1@W2)            -> bufA (bf16)
//   agg_out_q      : a2 = relu(di*(self+Σ h2') + b2); out = a2@Wc + bc
//
// Aggregation structure: ROW-MAJOR H[node][128]bf16, one node per 16-lane
// quarter (4/wave), full 256B row per gather. Evidence from rounds 2-4:
// feature-chunked variants (16B/64B/128B entries) were all SLOWER than this
// (84-200us vs 58us) despite equal-or-better line counts and even full L2
// residency (r3: FETCH 24MB, still 84us) -> aggs are LATENCY-bound with
// too little memory-level parallelism, not bytes/line/L2-capacity bound.
// This round: same structure, edge loop unrolled 8 -> 16 (16 uint4 gathers
// in flight per lane) to double per-wave MLP. Tail = one masked-16 iteration
// (dummy = self row, compensated analytically by acc -= pad*t).
// colidx is ushort (n <= 65536), halves index stream (validated r2-r4).
// bin_edges grid 256->1024 (was 1 block/CU).
// GEMMs: mfma_f32_16x16x32_bf16, wave = 16 rows x 128 cols, B-frags from
// prep-transposed bf16 W^T (L1-resident), C via LDS bounce. Requires n <= 65536.

typedef unsigned int uint;
typedef unsigned short ushort;
typedef __attribute__((ext_vector_type(8))) short bf16x8;
typedef __attribute__((ext_vector_type(4))) float f32x4;

#define NPB 256
#define MAXBKT 256
#define CAP 12288   // edges per bucket region; mean 8192, sd ~90

static __device__ __forceinline__ ushort f2bf(float f) {
    unsigned u = __float_as_uint(f);
    u += 0x7fffu + ((u >> 16) & 1u);   // round-to-nearest-even
    return (ushort)(u >> 16);
}
static __device__ __forceinline__ uint pack2(float a, float b) {
    return (uint)f2bf(a) | ((uint)f2bf(b) << 16);
}
static __device__ __forceinline__ float lo2f(uint u) { return __uint_as_float(u << 16); }
static __device__ __forceinline__ float hi2f(uint u) { return __uint_as_float(u & 0xffff0000u); }

#define UNPACK8(dst, u)                                        \
    dst[0] = lo2f(u.x); dst[1] = hi2f(u.x);                    \
    dst[2] = lo2f(u.y); dst[3] = hi2f(u.y);                    \
    dst[4] = lo2f(u.z); dst[5] = hi2f(u.z);                    \
    dst[6] = lo2f(u.w); dst[7] = hi2f(u.w);

// ---------------- CSR build (fixed-capacity buckets) ----------------

__global__ __launch_bounds__(256) void initcur(int* __restrict__ bcursor, int nbuckets) {
    int t = threadIdx.x;
    if (t < nbuckets) bcursor[t] = t * CAP;
}

__global__ __launch_bounds__(256) void bin_edges(const int* __restrict__ src,
                                                 const int* __restrict__ dst,
                                                 int* __restrict__ bcursor,
                                                 uint* __restrict__ pay,
                                                 int E, int nbuckets) {
    __shared__ int h[MAXBKT];
    __shared__ int base[MAXBKT];
    int tid = threadIdx.x;
    h[tid] = 0;
    __syncthreads();
    int chunk = (E + gridDim.x - 1) / gridDim.x;
    int i0 = blockIdx.x * chunk;
    int i1 = min(E, i0 + chunk);
    for (int i = i0 + tid; i < i1; i += 256) atomicAdd(&h[dst[i] >> 8], 1);
    __syncthreads();
    if (tid < nbuckets) base[tid] = h[tid] ? atomicAdd(&bcursor[tid], h[tid]) : 0;
    __syncthreads();
    h[tid] = 0;
    __syncthreads();
    for (int i = i0 + tid; i < i1; i += 256) {
        int d = dst[i];
        int b = d >> 8;
        int pos = base[b] + atomicAdd(&h[b], 1);
        pay[pos] = (uint)src[i] | ((uint)(d & 255) << 24);
    }
}

__global__ __launch_bounds__(256) void build_rows(const uint* __restrict__ pay,
                                                  const int* __restrict__ bcursor,
                                                  int* __restrict__ rowstart,
                                                  int* __restrict__ rowend,
                                                  float* __restrict__ dinv,
                                                  ushort* __restrict__ colidx, int n) {
    __shared__ int hist[NPB];
    __shared__ int sc[NPB];
    __shared__ int cur[NPB];
    int tid = threadIdx.x;
    int b = blockIdx.x;
    int node0 = b * NPB;
    int s = b * CAP, e = bcursor[b];

    hist[tid] = 0;
    __syncthreads();
    for (int i = s + tid; i < e; i += 256) atomicAdd(&hist[pay[i] >> 24], 1);
    __syncthreads();

    int v = hist[tid];
    sc[tid] = v;
    __syncthreads();
    for (int d = 1; d < 256; d <<= 1) {
        int x = (tid >= d) ? sc[tid - d] : 0;
        __syncthreads();
        sc[tid] += x;
        __syncthreads();
    }
    int excl = sc[tid] - v;
    cur[tid] = s + excl;
    int node = node0 + tid;
    if (node < n) {
        rowstart[node] = s + excl;
        rowend[node] = s + excl + v;
        dinv[node] = rsqrtf((float)(v + 1));  // +1 self-loop
    }
    __syncthreads();

    for (int i = s + tid; i < e; i += 256) {
        uint p = pay[i];
        int pos = atomicAdd(&cur[p >> 24], 1);
        colidx[pos] = (ushort)p;   // src < 65536
    }
}

// ---------------- W prep: bf16 transpose [n][k] for MFMA B-operand ----------
__global__ __launch_bounds__(256) void prep_wt(const float* __restrict__ W1,
                                               const float* __restrict__ W2,
                                               ushort* __restrict__ Wt1,
                                               ushort* __restrict__ Wt2) {
    int idx = blockIdx.x * 256 + threadIdx.x;  // 0..16383
    int k = idx >> 7, nn = idx & 127;
    Wt1[nn * 128 + k] = f2bf(W1[idx]);
    Wt2[nn * 128 + k] = f2bf(W2[idx]);
}

// ------- MFMA GEMM: Y[n x 128] = dinv ⊙ (X @ W), bf16 packed output -------
// Block 256 = 4 waves; wave computes 16 rows x 128 cols.
// mfma_f32_16x16x32_bf16 layouts (verified learn_hip m89/m120):
//   A[m][k]: m=lane&15, k=quad*8+j    B[k][n]: n=lane&15, k=quad*8+j
//   C/D:     col=lane&15, row=quad*4+reg
// B read from Wt[n][k] (transposed) -> 16B contiguous per lane, L1-resident.
template <bool A_BF16>
__global__ __launch_bounds__(256) void gemm_mfma(const void* __restrict__ Xv,
                                                 const ushort* __restrict__ Wt,
                                                 const float* __restrict__ dinv,
                                                 uint* __restrict__ Yb, int n) {
    __shared__ __align__(16) ushort sOut[4][16][136];  // pad: 272B row stride
    const int wave = threadIdx.x >> 6;
    const int lane = threadIdx.x & 63;
    const int quad = lane >> 4, l16 = lane & 15;
    const int m0 = blockIdx.x * 64 + wave * 16;

    f32x4 acc[8];
#pragma unroll
    for (int t = 0; t < 8; ++t) acc[t] = (f32x4){0.f, 0.f, 0.f, 0.f};

    int arow = m0 + l16;
    arow = arow < n ? arow : n - 1;

#pragma unroll
    for (int ks = 0; ks < 4; ++ks) {
        bf16x8 a;
        if (A_BF16) {
            const ushort* X = (const ushort*)Xv;
            a = *(const bf16x8*)&X[(size_t)arow * 128 + ks * 32 + quad * 8];
        } else {
            const float* X = (const float*)Xv;
            const float* px = &X[(size_t)arow * 128 + ks * 32 + quad * 8];
            float4 x0 = *(const float4*)px;
            float4 x1 = *(const float4*)(px + 4);
            ushort av[8] = {f2bf(x0.x), f2bf(x0.y), f2bf(x0.z), f2bf(x0.w),
                            f2bf(x1.x), f2bf(x1.y), f2bf(x1.z), f2bf(x1.w)};
            a = *(const bf16x8*)av;
        }
#pragma unroll
        for (int nt = 0; nt < 8; ++nt) {
            bf16x8 b = *(const bf16x8*)&Wt[(size_t)(nt * 16 + l16) * 128 + ks * 32 + quad * 8];
            acc[nt] = __builtin_amdgcn_mfma_f32_16x16x32_bf16(a, b, acc[nt], 0, 0, 0);
        }
    }

    // epilogue: scale rows by dinv, pack bf16 into LDS, coalesced store
    float dv[4];
#pragma unroll
    for (int r = 0; r < 4; ++r) {
        int rr = m0 + quad * 4 + r;
        dv[r] = dinv[rr < n ? rr : n - 1];
    }
#pragma unroll
    for (int nt = 0; nt < 8; ++nt)
#pragma unroll
        for (int r = 0; r < 4; ++r)
            sOut[wave][quad * 4 + r][nt * 16 + l16] = f2bf(acc[nt][r] * dv[r]);
    __syncthreads();

#pragma unroll
    for (int i = 0; i < 4; ++i) {
        int linear = i * 64 + lane;
        int row = linear >> 4, chunk = linear & 15;
        int rr = m0 + row;
        if (rr < n) {
            uint4 v = *(const uint4*)&sOut[wave][row][chunk * 8];
            *(uint4*)&Yb[(size_t)rr * 64 + chunk * 4] = v;
        }
    }
}

// ---------------- aggregate core: one node per 16-lane quarter ----------------
// Unmasked 16-edge main loop (16 uint4 rows in flight = 2x the prior MLP),
// one masked-16 tail iteration with dummy = self row (L1-hot) compensated
// analytically by acc -= pad * t.
static __device__ __forceinline__ void gather_q(const uint4* __restrict__ H4,
                                                int s, int e, int nn, int sub,
                                                const ushort* __restrict__ colidx,
                                                float acc[8]) {
    uint4 su = H4[(size_t)nn * 16 + sub];
    float t[8];
    UNPACK8(t, su);
#pragma unroll
    for (int j = 0; j < 8; ++j) acc[j] = t[j];   // self term (pre-scaled h')

    int p = s;
    for (; p + 16 <= e; p += 16) {
        int c[16];
#pragma unroll
        for (int i = 0; i < 16; ++i) c[i] = colidx[p + i];
        uint4 u[16];
#pragma unroll
        for (int i = 0; i < 16; ++i) u[i] = H4[(size_t)c[i] * 16 + sub];
#pragma unroll
        for (int i = 0; i < 16; ++i) {
            float a[8];
            UNPACK8(a, u[i]);
#pragma unroll
            for (int j = 0; j < 8; ++j) acc[j] += a[j];
        }
    }
    if (p < e) {
        int c[16];
#pragma unroll
        for (int i = 0; i < 16; ++i) c[i] = (p + i < e) ? (int)colidx[p + i] : nn;
        uint4 u[16];
#pragma unroll
        for (int i = 0; i < 16; ++i) u[i] = H4[(size_t)c[i] * 16 + sub];
#pragma unroll
        for (int i = 0; i < 16; ++i) {
            float a[8];
            UNPACK8(a, u[i]);
#pragma unroll
            for (int j = 0; j < 8; ++j) acc[j] += a[j];
        }
        float pad = (float)(p + 16 - e);   // dummies added self row 'pad' times
#pragma unroll
        for (int j = 0; j < 8; ++j) acc[j] -= pad * t[j];
    }
}

// middle layer: a1 = relu(di*sum + b1), bf16. 16 nodes/block.
__global__ __launch_bounds__(256) void agg_mid_q(const uint4* __restrict__ H4,
                                                 const int* __restrict__ rowstart,
                                                 const int* __restrict__ rowend,
                                                 const ushort* __restrict__ colidx,
                                                 const float* __restrict__ dinv,
                                                 const float* __restrict__ bias,
                                                 uint4* __restrict__ Ob, int n) {
    int tid = threadIdx.x;
    int sub = tid & 15;
    int node = blockIdx.x * 16 + (tid >> 4);
    int nn = node < n ? node : n - 1;
    int s = rowstart[nn], e = rowend[nn];
    float di = dinv[nn];

    float acc[8];
    gather_q(H4, s, e, nn, sub, colidx, acc);

    if (node < n) {
        float4 b0 = ((const float4*)bias)[sub * 2];
        float4 b1 = ((const float4*)bias)[sub * 2 + 1];
        float o0 = fmaxf(fmaf(acc[0], di, b0.x), 0.f);
        float o1 = fmaxf(fmaf(acc[1], di, b0.y), 0.f);
        float o2 = fmaxf(fmaf(acc[2], di, b0.z), 0.f);
        float o3 = fmaxf(fmaf(acc[3], di, b0.w), 0.f);
        float o4 = fmaxf(fmaf(acc[4], di, b1.x), 0.f);
        float o5 = fmaxf(fmaf(acc[5], di, b1.y), 0.f);
        float o6 = fmaxf(fmaf(acc[6], di, b1.z), 0.f);
        float o7 = fmaxf(fmaf(acc[7], di, b1.w), 0.f);
        uint4 ov;
        ov.x = pack2(o0, o1); ov.y = pack2(o2, o3);
        ov.z = pack2(o4, o5); ov.w = pack2(o6, o7);
        Ob[(size_t)node * 16 + sub] = ov;
    }
}

// final layer + classifier: a2 staged in LDS, 256 thr = 16 nodes x 16 cols.
__global__ __launch_bounds__(256) void agg_out_q(const uint4* __restrict__ H4,
                                                 const int* __restrict__ rowstart,
                                                 const int* __restrict__ rowend,
                                                 const ushort* __restrict__ colidx,
                                                 const float* __restrict__ dinv,
                                                 const float* __restrict__ bias,
                                                 const float* __restrict__ Wc,
                                                 const float* __restrict__ bc,
                                                 float* __restrict__ out, int n) {
    __shared__ float sA[16][129];
    int tid = threadIdx.x;
    int sub = tid & 15;
    int nl = tid >> 4;
    int node = blockIdx.x * 16 + nl;
    int nn = node < n ? node : n - 1;
    int s = rowstart[nn], e = rowend[nn];
    float di = dinv[nn];

    float acc[8];
    gather_q(H4, s, e, nn, sub, colidx, acc);

    {
        float4 b0 = ((const float4*)bias)[sub * 2];
        float4 b1 = ((const float4*)bias)[sub * 2 + 1];
        float f[8];
        f[0] = fmaxf(fmaf(acc[0], di, b0.x), 0.f);
        f[1] = fmaxf(fmaf(acc[1], di, b0.y), 0.f);
        f[2] = fmaxf(fmaf(acc[2], di, b0.z), 0.f);
        f[3] = fmaxf(fmaf(acc[3], di, b0.w), 0.f);
        f[4] = fmaxf(fmaf(acc[4], di, b1.x), 0.f);
        f[5] = fmaxf(fmaf(acc[5], di, b1.y), 0.f);
        f[6] = fmaxf(fmaf(acc[6], di, b1.z), 0.f);
        f[7] = fmaxf(fmaf(acc[7], di, b1.w), 0.f);
#pragma unroll
        for (int j = 0; j < 8; ++j) sA[nl][sub * 8 + j] = f[j];
    }
    __syncthreads();

    int col = tid & 15;
    float p0 = 0.f, p1 = 0.f;
#pragma unroll 4
    for (int k = 0; k < 128; k += 2) {
        p0 = fmaf(sA[nl][k], Wc[k * 16 + col], p0);
        p1 = fmaf(sA[nl][k + 1], Wc[(k + 1) * 16 + col], p1);
    }
    if (node < n) out[(size_t)node * 16 + col] = p0 + p1 + bc[col];
}

// ---------------- launch ----------------

extern "C" void kernel_launch(void* const* d_in, const int* in_sizes, int n_in,
                              void* d_out, int out_size, void* d_ws, size_t ws_size,
                              hipStream_t stream) {
    const float* x  = (const float*)d_in[0];
    const int*   ei = (const int*)d_in[1];
    const float* W1 = (const float*)d_in[2];
    const float* b1 = (const float*)d_in[3];
    const float* W2 = (const float*)d_in[4];
    const float* b2 = (const float*)d_in[5];
    const float* Wc = (const float*)d_in[6];
    const float* bc = (const float*)d_in[7];
    float* out = (float*)d_out;

    const int n = in_sizes[0] / 128;  // 50000
    const int E = in_sizes[1] / 2;    // 1,600,000
    const int* src = ei;
    const int* dst = ei + E;
    const int nbuckets = (n + NPB - 1) / NPB;  // 196

    char* p = (char*)d_ws;
    auto alloc = [&](size_t bytes) {
        char* q = p;
        p += (bytes + 255) & ~(size_t)255;
        return q;
    };
    int*    bcursor  = (int*)alloc(MAXBKT * 4);
    int*    rowstart = (int*)alloc((size_t)n * 4);
    int*    rowend   = (int*)alloc((size_t)n * 4);
    float*  dinv     = (float*)alloc((size_t)n * 4);
    ushort* Wt1      = (ushort*)alloc(128 * 128 * 2);
    ushort* Wt2      = (ushort*)alloc(128 * 128 * 2);
    uint*   pay      = (uint*)alloc((size_t)nbuckets * CAP * 4);
    ushort* colidx   = (ushort*)alloc((size_t)nbuckets * CAP * 2);
    uint*   bufA     = (uint*)alloc((size_t)n * 64 * 4);  // bf16 h'
    uint*   bufB     = (uint*)alloc((size_t)n * 64 * 4);  // bf16 a1
    if ((size_t)(p - (char*)d_ws) > ws_size) return;

    initcur<<<1, 256, 0, stream>>>(bcursor, nbuckets);
    bin_edges<<<1024, 256, 0, stream>>>(src, dst, bcursor, pay, E, nbuckets);
    build_rows<<<nbuckets, 256, 0, stream>>>(pay, bcursor, rowstart, rowend, dinv, colidx, n);
    prep_wt<<<64, 256, 0, stream>>>(W1, W2, Wt1, Wt2);

    const int gemmb = (n + 63) / 64;
    const int aggb = (n + 15) / 16;
    gemm_mfma<false><<<gemmb, 256, 0, stream>>>(x, Wt1, dinv, bufA, n);
    agg_mid_q<<<aggb, 256, 0, stream>>>((const uint4*)bufA, rowstart, rowend, colidx,
                                        dinv, b1, (uint4*)bufB, n);
    gemm_mfma<true><<<gemmb, 256, 0, stream>>>(bufB, Wt2, dinv, bufA, n);
    agg_out_q<<<aggb, 256, 0, stream>>>((const uint4*)bufA, rowstart, rowend, colidx,
                                        dinv, b2, Wc, bc, out, n);
}